// Round 4
// baseline (624.592 us; speedup 1.0000x reference)
//
#include <hip/hip_runtime.h>
#include <math.h>

#define B_N 32768
#define A_N 6
#define H_N 256
#define D_N 128
#define K_N 2048

// Block compiler from contracting a*a into subsequent adds (np computes z*z array, then sums it)
__device__ __forceinline__ float sqf(float v) {
    float s = v * v;
    asm volatile("" : "+v"(s));
    return s;
}

// numpy pairwise_sum for n=128 contiguous fp32 (loops_arithm_fp.dispatch.c.src):
// 8 accumulators stride-8 ("8 times unroll ... without changing summation ordering"),
// r[j] = sequential sum of x[j], x[8+j], ..., x[120+j]; then fixed 3-level tree.
// Bitwise replication of np.sum(x*x, axis=-1) for row length 128.
__device__ __forceinline__ float np_sumsq_128(const float* __restrict__ p)
{
    float r[8];
#pragma unroll
    for (int j = 0; j < 8; j++) r[j] = sqf(p[j]);
#pragma unroll
    for (int i = 8; i < 128; i += 8) {
#pragma unroll
        for (int j = 0; j < 8; j++) r[j] = r[j] + sqf(p[i + j]);
    }
    return ((r[0] + r[1]) + (r[2] + r[3])) + ((r[4] + r[5]) + (r[6] + r[7]));
}

// az2[r] = np-exact sum(z_r^2)
__global__ __launch_bounds__(256) void rowsum_kernel(const float* __restrict__ z,
                                                     float* __restrict__ az2)
{
    int r = blockIdx.x * 256 + threadIdx.x;
    az2[r] = np_sumsq_128(z + (long)r * D_N);
}

// e2[k] = np-exact sum(emb_k^2)
__global__ __launch_bounds__(256) void embsum_kernel(const float* __restrict__ emb,
                                                     float* __restrict__ e2)
{
    int k = blockIdx.x * 256 + threadIdx.x;
    e2[k] = np_sumsq_128(emb + (long)k * D_N);
}

// ---------------- encoder layer 1: h1 = relu(action @ We1 + be1), fp32 fma chain ----------------
__global__ __launch_bounds__(256) void enc1_kernel(const float* __restrict__ action,
    const float* __restrict__ W, const float* __restrict__ bias, float* __restrict__ out)
{
    __shared__ float as[8][6];
    int tid = threadIdx.x;
    int row0 = blockIdx.x * 8;
    if (tid < 48) as[tid / 6][tid % 6] = action[(long)(row0 + tid / 6) * A_N + tid % 6];
    __syncthreads();
    int col = tid;
    float w[6];
#pragma unroll
    for (int k = 0; k < 6; k++) w[k] = W[k * H_N + col];
    float bv = bias[col];   // zeros: chain starts at 0, +0 is exact
#pragma unroll
    for (int r = 0; r < 8; r++) {
        float acc = bv;
#pragma unroll
        for (int k = 0; k < 6; k++) acc = fmaf(as[r][k], w[k], acc);
        out[(long)(row0 + r) * H_N + col] = fmaxf(acc, 0.0f);
    }
}

// ---------------- register-tiled fp32 GEMM: O = act(A @ W + b), ascending-k fmaf chain ----------------
// == OpenBLAS sgemm microkernel semantics (one accumulator per C element, ascending k, beta=0),
// bias added after the chain (exact for zero biases, and matches np's separate broadcast add).
template<int RELU, int GATHER>
__global__ __launch_bounds__(256) void gemm_rt(const float* __restrict__ Amat,
    const float* __restrict__ W, const float* __restrict__ bias,
    float* __restrict__ Omat, int Kdim, int N, const int* __restrict__ gidx)
{
    __shared__ float As[128][20];
    __shared__ float Bs[16][132];
    int tid = threadIdx.x;
    int tx = tid & 15, ty = tid >> 4;
    int row0 = blockIdx.y * 128;
    int col0 = blockIdx.x * 128;
    float acc[8][8];
#pragma unroll
    for (int i = 0; i < 8; i++)
#pragma unroll
        for (int j = 0; j < 8; j++) acc[i][j] = 0.0f;

    for (int k0 = 0; k0 < Kdim; k0 += 16) {
        for (int f = tid; f < 512; f += 256) {
            int r = f >> 2, k4 = (f & 3) * 4;
            long arow = row0 + r;
            long abase = GATHER ? (long)gidx[arow] * Kdim : arow * (long)Kdim;
            *(float4*)&As[r][k4] = *(const float4*)&Amat[abase + k0 + k4];
        }
        for (int f = tid; f < 512; f += 256) {
            int kr = f >> 5, c4 = (f & 31) * 4;
            *(float4*)&Bs[kr][c4] = *(const float4*)&W[(long)(k0 + kr) * N + col0 + c4];
        }
        __syncthreads();
#pragma unroll
        for (int kk = 0; kk < 16; kk += 4) {
            float a_[8][4], b_[4][8];
#pragma unroll
            for (int i = 0; i < 8; i++) {
                float4 v = *(const float4*)&As[ty * 8 + i][kk];
                a_[i][0] = v.x; a_[i][1] = v.y; a_[i][2] = v.z; a_[i][3] = v.w;
            }
#pragma unroll
            for (int q = 0; q < 4; q++) {
                float4 v = *(const float4*)&Bs[kk + q][tx * 8];
                float4 u = *(const float4*)&Bs[kk + q][tx * 8 + 4];
                b_[q][0] = v.x; b_[q][1] = v.y; b_[q][2] = v.z; b_[q][3] = v.w;
                b_[q][4] = u.x; b_[q][5] = u.y; b_[q][6] = u.z; b_[q][7] = u.w;
            }
#pragma unroll
            for (int q = 0; q < 4; q++)
#pragma unroll
                for (int i = 0; i < 8; i++)
#pragma unroll
                    for (int j = 0; j < 8; j++)
                        acc[i][j] = fmaf(a_[i][q], b_[q][j], acc[i][j]);
        }
        __syncthreads();
    }
#pragma unroll
    for (int i = 0; i < 8; i++) {
        long r = row0 + ty * 8 + i;
#pragma unroll
        for (int j4 = 0; j4 < 8; j4 += 4) {
            int c = col0 + tx * 8 + j4;
            float4 o;
            o.x = acc[i][j4 + 0] + bias[c + 0];
            o.y = acc[i][j4 + 1] + bias[c + 1];
            o.z = acc[i][j4 + 2] + bias[c + 2];
            o.w = acc[i][j4 + 3] + bias[c + 3];
            if (RELU) {
                o.x = fmaxf(o.x, 0.0f); o.y = fmaxf(o.y, 0.0f);
                o.z = fmaxf(o.z, 0.0f); o.w = fmaxf(o.w, 0.0f);
            }
            *(float4*)&Omat[r * N + c] = o;
        }
    }
}

// ---------------- VQ: per (128-row, 128-code) block: np-exact d2, per-tile argmin ----------------
// d2 = fl(fl(az2[r] + e2[k]) - 2*C_rk), C_rk = ascending-d fmaf chain == acc[i][j].
// (t1 - 2*acc may compile to fma(-2,acc,t1): identical bits since 2*acc is exact.)
__global__ __launch_bounds__(256) void vq_topk(const float* __restrict__ z,
    const float* __restrict__ emb, const float* __restrict__ e2,
    const float* __restrict__ az2, float2* __restrict__ tw /* [B][16] = (val, idx-bits) */)
{
    __shared__ float As[128][20];
    __shared__ float Bs[16][132];
    __shared__ float redv[128][16];
    __shared__ int   redi[128][16];
    int tid = threadIdx.x;
    int tx = tid & 15, ty = tid >> 4;
    int row0 = blockIdx.y * 128;
    int col0 = blockIdx.x * 128;
    float acc[8][8];
#pragma unroll
    for (int i = 0; i < 8; i++)
#pragma unroll
        for (int j = 0; j < 8; j++) acc[i][j] = 0.0f;

    for (int k0 = 0; k0 < D_N; k0 += 16) {
        for (int f = tid; f < 512; f += 256) {
            int r = f >> 2, k4 = (f & 3) * 4;
            *(float4*)&As[r][k4] = *(const float4*)&z[(long)(row0 + r) * D_N + k0 + k4];
        }
        for (int f = tid; f < 512; f += 256) {
            int c = f >> 2, k4 = (f & 3) * 4;
            float4 v = *(const float4*)&emb[(long)(col0 + c) * D_N + k0 + k4];
            Bs[k4 + 0][c] = v.x; Bs[k4 + 1][c] = v.y; Bs[k4 + 2][c] = v.z; Bs[k4 + 3][c] = v.w;
        }
        __syncthreads();
#pragma unroll
        for (int kk = 0; kk < 16; kk += 4) {
            float a_[8][4], b_[4][8];
#pragma unroll
            for (int i = 0; i < 8; i++) {
                float4 v = *(const float4*)&As[ty * 8 + i][kk];
                a_[i][0] = v.x; a_[i][1] = v.y; a_[i][2] = v.z; a_[i][3] = v.w;
            }
#pragma unroll
            for (int q = 0; q < 4; q++) {
                float4 v = *(const float4*)&Bs[kk + q][tx * 8];
                float4 u = *(const float4*)&Bs[kk + q][tx * 8 + 4];
                b_[q][0] = v.x; b_[q][1] = v.y; b_[q][2] = v.z; b_[q][3] = v.w;
                b_[q][4] = u.x; b_[q][5] = u.y; b_[q][6] = u.z; b_[q][7] = u.w;
            }
#pragma unroll
            for (int q = 0; q < 4; q++)
#pragma unroll
                for (int i = 0; i < 8; i++)
#pragma unroll
                    for (int j = 0; j < 8; j++)
                        acc[i][j] = fmaf(a_[i][q], b_[q][j], acc[i][j]);
        }
        __syncthreads();
    }

    float e2v[8];
#pragma unroll
    for (int j = 0; j < 8; j++) e2v[j] = e2[col0 + tx * 8 + j];
#pragma unroll
    for (int i = 0; i < 8; i++) {
        float Ar = az2[row0 + ty * 8 + i];
        float bv = 1e30f; int bi = 0;
#pragma unroll
        for (int j = 0; j < 8; j++) {
            float t1 = Ar + e2v[j];           // fl(A + B)
            float d2 = t1 - 2.0f * acc[i][j]; // fl(T1 - 2C)
            int k = col0 + tx * 8 + j;
            if (d2 < bv) { bv = d2; bi = k; } // j ascending: strict < keeps first min
        }
        redv[ty * 8 + i][tx] = bv;
        redi[ty * 8 + i][tx] = bi;
    }
    __syncthreads();
    if (tid < 128) {
        float bv = 1e30f; int bi = 0;
        for (int t = 0; t < 16; t++) {
            float v = redv[tid][t]; int k = redi[tid][t];
            if (v < bv || (v == bv && k < bi)) { bv = v; bi = k; }
        }
        tw[(long)(row0 + tid) * 16 + blockIdx.x] = make_float2(bv, __int_as_float(bi));
    }
}

// ---------------- merge 16 tile winners (first-min), final idx ----------------
__global__ __launch_bounds__(256) void vq_pick(const float2* __restrict__ tw,
    int* __restrict__ idxI, float* __restrict__ outIdx)
{
    int r = blockIdx.x * 256 + threadIdx.x;
    float bv = 1e30f; int bi = 0;
    for (int t = 0; t < 16; t++) {
        float2 c = tw[(long)r * 16 + t];
        int k = __float_as_int(c.y);
        if (c.x < bv || (c.x == bv && k < bi)) { bv = c.x; bi = k; }
    }
    idxI[r] = bi;
    outIdx[r] = (float)bi;
}

// ---------------- vq loss partial sums ----------------
__global__ __launch_bounds__(256) void vqloss_kernel(const float* __restrict__ z,
    const float* __restrict__ emb, const int* __restrict__ idxI, float* __restrict__ part)
{
    __shared__ float red[256];
    int tid = threadIdx.x;
    int row0 = blockIdx.x * 64;
    float s = 0.0f;
    for (int e = tid; e < 64 * D_N; e += 256) {
        int r = row0 + (e >> 7), d = e & 127;
        float diff = z[(long)r * D_N + d] - emb[(long)idxI[r] * D_N + d];
        s = fmaf(diff, diff, s);
    }
    red[tid] = s; __syncthreads();
    for (int o = 128; o > 0; o >>= 1) { if (tid < o) red[tid] += red[tid + o]; __syncthreads(); }
    if (tid == 0) part[blockIdx.x] = red[0];
}

// ---------------- head: recons = tanh(d2 @ Wh + bh), partial recon loss ----------------
__global__ __launch_bounds__(256) void head_kernel(const float* __restrict__ dbuf,
    const float* __restrict__ Wh, const float* __restrict__ bh,
    const float* __restrict__ action, float* __restrict__ outRec, float* __restrict__ part)
{
    __shared__ float WhS[H_N * A_N];
    __shared__ float red[256];
    int tid = threadIdx.x;
    for (int i = tid; i < H_N * A_N; i += 256) WhS[i] = Wh[i];
    __syncthreads();
    long t = (long)blockIdx.x * 256 + tid;
    int row = (int)(t / 6), col = (int)(t % 6);
    const float* dr = dbuf + (long)row * H_N;
    float acc = bh[col];
    for (int k = 0; k < H_N; k++) acc = fmaf(dr[k], WhS[k * 6 + col], acc);
    float rec = tanhf(acc);
    outRec[t] = rec;
    float diff = rec - action[t];
    red[tid] = diff * diff;
    __syncthreads();
    for (int o = 128; o > 0; o >>= 1) { if (tid < o) red[tid] += red[tid + o]; __syncthreads(); }
    if (tid == 0) part[blockIdx.x] = red[0];
}

// ---------------- finalize scalars ----------------
__global__ void final_kernel(const float* __restrict__ vqp, const float* __restrict__ recp,
                             float* __restrict__ out)
{
    if (threadIdx.x == 0 && blockIdx.x == 0) {
        double vs = 0.0;
        for (int i = 0; i < 512; i++) vs += (double)vqp[i];
        double rs = 0.0;
        for (int i = 0; i < 768; i++) rs += (double)recp[i];
        double m = vs / 4194304.0;           // B*D
        double vql = 1.25 * m;               // beta*commit + embed (forward-equal)
        double rl = rs / 196608.0;           // B*A
        out[0] = (float)(rl + vql);
        out[1] = (float)vql;
        out[2] = (float)rl;
    }
}

extern "C" void kernel_launch(void* const* d_in, const int* in_sizes, int n_in,
                              void* d_out, int out_size, void* d_ws, size_t ws_size,
                              hipStream_t stream)
{
    (void)in_sizes; (void)n_in; (void)out_size; (void)ws_size;
    const float* action = (const float*)d_in[0];
    const float* We1 = (const float*)d_in[1];
    const float* be1 = (const float*)d_in[2];
    const float* We2 = (const float*)d_in[3];
    const float* be2 = (const float*)d_in[4];
    const float* We3 = (const float*)d_in[5];
    const float* be3 = (const float*)d_in[6];
    const float* emb = (const float*)d_in[7];
    const float* Wd1 = (const float*)d_in[8];
    const float* bd1 = (const float*)d_in[9];
    const float* Wd2 = (const float*)d_in[10];
    const float* bd2 = (const float*)d_in[11];
    const float* Wh  = (const float*)d_in[12];
    const float* bh  = (const float*)d_in[13];
    float* out = (float*)d_out;

    // workspace layout (~84 MB):
    //   h1 : B*H floats (33.5 MB) -- front 4 MB aliased as tw between vq_topk and vq_pick
    //   h2 : B*H floats (33.5 MB)
    //   z  : B*D floats (16.8 MB)
    //   tail: az2(B) e2(K) idxI(B) vqp(512) recp(768)
    float* h1 = (float*)d_ws;
    float* h2 = h1 + (long)B_N * H_N;
    float* z  = h2 + (long)B_N * H_N;
    float* az2 = z + (long)B_N * D_N;
    float* e2  = az2 + B_N;
    int*   idxI = (int*)(e2 + K_N);
    float* vqp  = (float*)(idxI + B_N);
    float* recp = vqp + 512;
    float2* tw  = (float2*)h1;   // B*16 float2 = 4 MB, live only topk->pick (h1 dead there)

    // encoder (fp32 ascending-k fma chains == OpenBLAS sgemm microkernel semantics)
    enc1_kernel<<<B_N / 8, 256, 0, stream>>>(action, We1, be1, h1);
    gemm_rt<1, 0><<<dim3(2, B_N / 128), 256, 0, stream>>>(h1, We2, be2, h2, H_N, H_N, nullptr);
    gemm_rt<0, 0><<<dim3(1, B_N / 128), 256, 0, stream>>>(h2, We3, be3, z, H_N, D_N, nullptr);

    // np-exact squared norms (numpy pairwise_sum 8-accumulator tree)
    rowsum_kernel<<<B_N / 256, 256, 0, stream>>>(z, az2);
    embsum_kernel<<<K_N / 256, 256, 0, stream>>>(emb, e2);

    // vector quantizer: np-exact fp32 d2 + first-min argmin
    vq_topk<<<dim3(K_N / 128, B_N / 128), 256, 0, stream>>>(z, emb, e2, az2, tw);
    vq_pick<<<B_N / 256, 256, 0, stream>>>(tw, idxI, out + 3);
    vqloss_kernel<<<B_N / 64, 256, 0, stream>>>(z, emb, idxI, vqp);

    // decoder (dec1 gathers q = emb[idx]; h1/tw dead by now)
    gemm_rt<1, 1><<<dim3(2, B_N / 128), 256, 0, stream>>>(emb, Wd1, bd1, h1, D_N, H_N, idxI);
    gemm_rt<1, 0><<<dim3(2, B_N / 128), 256, 0, stream>>>(h1, Wd2, bd2, h2, H_N, H_N, nullptr);

    // head + losses
    head_kernel<<<(B_N * A_N) / 256, 256, 0, stream>>>(h2, Wh, bh, action, out + 3 + B_N, recp);
    final_kernel<<<1, 64, 0, stream>>>(vqp, recp, out);
}

// Round 5
// 530.325 us; speedup vs baseline: 1.1778x; 1.1778x over previous
//
#include <hip/hip_runtime.h>
#include <math.h>

#define B_N 32768
#define A_N 6
#define H_N 256
#define D_N 128
#define K_N 2048

// Block compiler from contracting a*a into subsequent adds (np computes z*z array, then sums it)
__device__ __forceinline__ float sqf(float v) {
    float s = v * v;
    asm volatile("" : "+v"(s));
    return s;
}

// numpy pairwise_sum for n=128 contiguous fp32 (loops_arithm_fp.dispatch.c.src):
// 8 accumulators stride-8, r[j] = sequential sum of x[j], x[8+j], ..., x[120+j];
// then fixed 3-level tree. Bitwise replication of np.sum(x*x, axis=-1) for n=128.
// PROTECTED SEMANTICS: do not alter the add order.
__device__ __forceinline__ float np_sumsq_128(const float* __restrict__ p)
{
    float r[8];
#pragma unroll
    for (int j = 0; j < 8; j++) r[j] = sqf(p[j]);
#pragma unroll
    for (int i = 8; i < 128; i += 8) {
#pragma unroll
        for (int j = 0; j < 8; j++) r[j] = r[j] + sqf(p[i + j]);
    }
    return ((r[0] + r[1]) + (r[2] + r[3])) + ((r[4] + r[5]) + (r[6] + r[7]));
}

// az2[r] = np-exact sum(z_r^2)
__global__ __launch_bounds__(256) void rowsum_kernel(const float* __restrict__ z,
                                                     float* __restrict__ az2)
{
    int r = blockIdx.x * 256 + threadIdx.x;
    az2[r] = np_sumsq_128(z + (long)r * D_N);
}

// e2[k] = np-exact sum(emb_k^2)
__global__ __launch_bounds__(256) void embsum_kernel(const float* __restrict__ emb,
                                                     float* __restrict__ e2)
{
    int k = blockIdx.x * 256 + threadIdx.x;
    e2[k] = np_sumsq_128(emb + (long)k * D_N);
}

// ---------------- encoder layer 1: h1 = relu(action @ We1 + be1), fp32 fma chain ----------------
__global__ __launch_bounds__(256) void enc1_kernel(const float* __restrict__ action,
    const float* __restrict__ W, const float* __restrict__ bias, float* __restrict__ out)
{
    __shared__ float as[8][6];
    int tid = threadIdx.x;
    int row0 = blockIdx.x * 8;
    if (tid < 48) as[tid / 6][tid % 6] = action[(long)(row0 + tid / 6) * A_N + tid % 6];
    __syncthreads();
    int col = tid;
    float w[6];
#pragma unroll
    for (int k = 0; k < 6; k++) w[k] = W[k * H_N + col];
    float bv = bias[col];
#pragma unroll
    for (int r = 0; r < 8; r++) {
        float acc = bv;
#pragma unroll
        for (int k = 0; k < 6; k++) acc = fmaf(as[r][k], w[k], acc);
        out[(long)(row0 + r) * H_N + col] = fmaxf(acc, 0.0f);
    }
}

// ---------------- register-tiled fp32 GEMM: O = act(A @ W + b), ascending-k fmaf chain ----------------
// Conflict-free LDS layout: BOTH tiles k-major with 132-float row pad.
//   A-frag read: As[kk][ty*8 + {0..3,4..7}] -> row offsets {0,8,16,24}+... mod 32, conflict-free.
//   B-frag read: Bs[kk][{4tx, 64+4tx}]      -> <=2-way (free on CDNA4, m136).
// Per-acc chain order: kk ascending, k0 ascending == OpenBLAS ascending-k fmaf chain (z bits protected).
template<int RELU, int GATHER>
__global__ __launch_bounds__(256) void gemm_rt(const float* __restrict__ Amat,
    const float* __restrict__ W, const float* __restrict__ bias,
    float* __restrict__ Omat, int Kdim, int N, const int* __restrict__ gidx)
{
    __shared__ float As[16][132];   // k-major: As[k][row]
    __shared__ float Bs[16][132];   // k-major: Bs[k][col]
    int tid = threadIdx.x;
    int tx = tid & 15, ty = tid >> 4;
    int row0 = blockIdx.y * 128;
    int col0 = blockIdx.x * 128;
    float acc[8][8];
#pragma unroll
    for (int i = 0; i < 8; i++)
#pragma unroll
        for (int j = 0; j < 8; j++) acc[i][j] = 0.0f;

    for (int k0 = 0; k0 < Kdim; k0 += 16) {
        // stage A (transposed scatter; 2-way write aliasing only)
        for (int f = tid; f < 512; f += 256) {
            int r = f >> 2, k4 = (f & 3) * 4;
            long arow = row0 + r;
            long abase = GATHER ? (long)gidx[arow] * Kdim : arow * (long)Kdim;
            float4 v = *(const float4*)&Amat[abase + k0 + k4];
            As[k4 + 0][r] = v.x; As[k4 + 1][r] = v.y; As[k4 + 2][r] = v.z; As[k4 + 3][r] = v.w;
        }
        // stage B (already k-major in W)
        for (int f = tid; f < 512; f += 256) {
            int kr = f >> 5, c4 = (f & 31) * 4;
            *(float4*)&Bs[kr][c4] = *(const float4*)&W[(long)(k0 + kr) * N + col0 + c4];
        }
        __syncthreads();
#pragma unroll
        for (int kk = 0; kk < 16; kk++) {
            float4 a0 = *(const float4*)&As[kk][ty * 8];
            float4 a1 = *(const float4*)&As[kk][ty * 8 + 4];
            float4 b0 = *(const float4*)&Bs[kk][tx * 4];
            float4 b1 = *(const float4*)&Bs[kk][64 + tx * 4];
            float av[8] = {a0.x, a0.y, a0.z, a0.w, a1.x, a1.y, a1.z, a1.w};
            float bv[8] = {b0.x, b0.y, b0.z, b0.w, b1.x, b1.y, b1.z, b1.w};
#pragma unroll
            for (int i = 0; i < 8; i++)
#pragma unroll
                for (int j = 0; j < 8; j++)
                    acc[i][j] = fmaf(av[i], bv[j], acc[i][j]);
        }
        __syncthreads();
    }
#pragma unroll
    for (int i = 0; i < 8; i++) {
        long r = row0 + ty * 8 + i;
        int c0 = col0 + tx * 4;
        int c1 = col0 + 64 + tx * 4;
        float4 o0, o1;
        o0.x = acc[i][0] + bias[c0 + 0];
        o0.y = acc[i][1] + bias[c0 + 1];
        o0.z = acc[i][2] + bias[c0 + 2];
        o0.w = acc[i][3] + bias[c0 + 3];
        o1.x = acc[i][4] + bias[c1 + 0];
        o1.y = acc[i][5] + bias[c1 + 1];
        o1.z = acc[i][6] + bias[c1 + 2];
        o1.w = acc[i][7] + bias[c1 + 3];
        if (RELU) {
            o0.x = fmaxf(o0.x, 0.0f); o0.y = fmaxf(o0.y, 0.0f);
            o0.z = fmaxf(o0.z, 0.0f); o0.w = fmaxf(o0.w, 0.0f);
            o1.x = fmaxf(o1.x, 0.0f); o1.y = fmaxf(o1.y, 0.0f);
            o1.z = fmaxf(o1.z, 0.0f); o1.w = fmaxf(o1.w, 0.0f);
        }
        *(float4*)&Omat[r * N + c0] = o0;
        *(float4*)&Omat[r * N + c1] = o1;
    }
}

// ---------------- VQ: per (128-row, 128-code) block: np-exact d2, per-tile argmin ----------------
// d2 = fl(fl(az2[r] + e2[k]) - 2*C_rk), C_rk = ascending-d fmaf chain (PROTECTED).
// Same conflict-free layout as gemm_rt; per-row argmin via 16-lane shfl_xor butterfly.
__global__ __launch_bounds__(256) void vq_topk(const float* __restrict__ z,
    const float* __restrict__ emb, const float* __restrict__ e2,
    const float* __restrict__ az2, float2* __restrict__ tw /* [B][16] = (val, idx-bits) */)
{
    __shared__ float As[16][132];   // k-major: As[d][row]
    __shared__ float Bs[16][132];   // k-major: Bs[d][code]
    int tid = threadIdx.x;
    int tx = tid & 15, ty = tid >> 4;
    int row0 = blockIdx.y * 128;
    int col0 = blockIdx.x * 128;
    float acc[8][8];
#pragma unroll
    for (int i = 0; i < 8; i++)
#pragma unroll
        for (int j = 0; j < 8; j++) acc[i][j] = 0.0f;

    for (int k0 = 0; k0 < D_N; k0 += 16) {
        for (int f = tid; f < 512; f += 256) {
            int r = f >> 2, k4 = (f & 3) * 4;
            float4 v = *(const float4*)&z[(long)(row0 + r) * D_N + k0 + k4];
            As[k4 + 0][r] = v.x; As[k4 + 1][r] = v.y; As[k4 + 2][r] = v.z; As[k4 + 3][r] = v.w;
        }
        for (int f = tid; f < 512; f += 256) {
            int c = f >> 2, k4 = (f & 3) * 4;
            float4 v = *(const float4*)&emb[(long)(col0 + c) * D_N + k0 + k4];
            Bs[k4 + 0][c] = v.x; Bs[k4 + 1][c] = v.y; Bs[k4 + 2][c] = v.z; Bs[k4 + 3][c] = v.w;
        }
        __syncthreads();
#pragma unroll
        for (int kk = 0; kk < 16; kk++) {
            float4 a0 = *(const float4*)&As[kk][ty * 8];
            float4 a1 = *(const float4*)&As[kk][ty * 8 + 4];
            float4 b0 = *(const float4*)&Bs[kk][tx * 4];
            float4 b1 = *(const float4*)&Bs[kk][64 + tx * 4];
            float av[8] = {a0.x, a0.y, a0.z, a0.w, a1.x, a1.y, a1.z, a1.w};
            float bv[8] = {b0.x, b0.y, b0.z, b0.w, b1.x, b1.y, b1.z, b1.w};
#pragma unroll
            for (int i = 0; i < 8; i++)
#pragma unroll
                for (int j = 0; j < 8; j++)
                    acc[i][j] = fmaf(av[i], bv[j], acc[i][j]);
        }
        __syncthreads();
    }

    // epilogue: np-exact d2, per-thread first-min over its 8 codes (ascending k), butterfly over tx
    float e2v[8];
#pragma unroll
    for (int j = 0; j < 4; j++) e2v[j] = e2[col0 + tx * 4 + j];
#pragma unroll
    for (int j = 0; j < 4; j++) e2v[4 + j] = e2[col0 + 64 + tx * 4 + j];

#pragma unroll
    for (int i = 0; i < 8; i++) {
        float Ar = az2[row0 + ty * 8 + i];
        float bv = 1e30f; int bi = 0;
#pragma unroll
        for (int j = 0; j < 8; j++) {
            float t1 = Ar + e2v[j];           // fl(A + B)
            float d2 = t1 - 2.0f * acc[i][j]; // fl(T1 - 2C)
            int k = col0 + (j < 4 ? tx * 4 + j : 64 + tx * 4 + (j - 4));
            if (d2 < bv) { bv = d2; bi = k; } // ascending k: strict < keeps first min
        }
#pragma unroll
        for (int m = 1; m < 16; m <<= 1) {
            float ov = __shfl_xor(bv, m, 16);
            int   oi = __shfl_xor(bi, m, 16);
            if (ov < bv || (ov == bv && oi < bi)) { bv = ov; bi = oi; }
        }
        if (tx == 0)
            tw[(long)(row0 + ty * 8 + i) * 16 + blockIdx.x] = make_float2(bv, __int_as_float(bi));
    }
}

// ---------------- merge 16 tile winners (first-min), final idx ----------------
__global__ __launch_bounds__(256) void vq_pick(const float2* __restrict__ tw,
    int* __restrict__ idxI, float* __restrict__ outIdx)
{
    int r = blockIdx.x * 256 + threadIdx.x;
    float bv = 1e30f; int bi = 0;
    for (int t = 0; t < 16; t++) {
        float2 c = tw[(long)r * 16 + t];
        int k = __float_as_int(c.y);
        if (c.x < bv || (c.x == bv && k < bi)) { bv = c.x; bi = k; }
    }
    idxI[r] = bi;
    outIdx[r] = (float)bi;
}

// ---------------- vq loss partial sums ----------------
__global__ __launch_bounds__(256) void vqloss_kernel(const float* __restrict__ z,
    const float* __restrict__ emb, const int* __restrict__ idxI, float* __restrict__ part)
{
    __shared__ float red[256];
    int tid = threadIdx.x;
    int row0 = blockIdx.x * 64;
    float s = 0.0f;
    for (int e = tid; e < 64 * D_N; e += 256) {
        int r = row0 + (e >> 7), d = e & 127;
        float diff = z[(long)r * D_N + d] - emb[(long)idxI[r] * D_N + d];
        s = fmaf(diff, diff, s);
    }
    red[tid] = s; __syncthreads();
    for (int o = 128; o > 0; o >>= 1) { if (tid < o) red[tid] += red[tid + o]; __syncthreads(); }
    if (tid == 0) part[blockIdx.x] = red[0];
}

// ---------------- head: recons = tanh(d2 @ Wh + bh), partial recon loss ----------------
__global__ __launch_bounds__(256) void head_kernel(const float* __restrict__ dbuf,
    const float* __restrict__ Wh, const float* __restrict__ bh,
    const float* __restrict__ action, float* __restrict__ outRec, float* __restrict__ part)
{
    __shared__ float WhS[H_N * A_N];
    __shared__ float red[256];
    int tid = threadIdx.x;
    for (int i = tid; i < H_N * A_N; i += 256) WhS[i] = Wh[i];
    __syncthreads();
    long t = (long)blockIdx.x * 256 + tid;
    int row = (int)(t / 6), col = (int)(t % 6);
    const float* dr = dbuf + (long)row * H_N;
    float acc = bh[col];
    for (int k = 0; k < H_N; k++) acc = fmaf(dr[k], WhS[k * 6 + col], acc);
    float rec = tanhf(acc);
    outRec[t] = rec;
    float diff = rec - action[t];
    red[tid] = diff * diff;
    __syncthreads();
    for (int o = 128; o > 0; o >>= 1) { if (tid < o) red[tid] += red[tid + o]; __syncthreads(); }
    if (tid == 0) part[blockIdx.x] = red[0];
}

// ---------------- finalize scalars ----------------
__global__ void final_kernel(const float* __restrict__ vqp, const float* __restrict__ recp,
                             float* __restrict__ out)
{
    if (threadIdx.x == 0 && blockIdx.x == 0) {
        double vs = 0.0;
        for (int i = 0; i < 512; i++) vs += (double)vqp[i];
        double rs = 0.0;
        for (int i = 0; i < 768; i++) rs += (double)recp[i];
        double m = vs / 4194304.0;           // B*D
        double vql = 1.25 * m;               // beta*commit + embed (forward-equal)
        double rl = rs / 196608.0;           // B*A
        out[0] = (float)(rl + vql);
        out[1] = (float)vql;
        out[2] = (float)rl;
    }
}

extern "C" void kernel_launch(void* const* d_in, const int* in_sizes, int n_in,
                              void* d_out, int out_size, void* d_ws, size_t ws_size,
                              hipStream_t stream)
{
    (void)in_sizes; (void)n_in; (void)out_size; (void)ws_size;
    const float* action = (const float*)d_in[0];
    const float* We1 = (const float*)d_in[1];
    const float* be1 = (const float*)d_in[2];
    const float* We2 = (const float*)d_in[3];
    const float* be2 = (const float*)d_in[4];
    const float* We3 = (const float*)d_in[5];
    const float* be3 = (const float*)d_in[6];
    const float* emb = (const float*)d_in[7];
    const float* Wd1 = (const float*)d_in[8];
    const float* bd1 = (const float*)d_in[9];
    const float* Wd2 = (const float*)d_in[10];
    const float* bd2 = (const float*)d_in[11];
    const float* Wh  = (const float*)d_in[12];
    const float* bh  = (const float*)d_in[13];
    float* out = (float*)d_out;

    // workspace layout (~84 MB):
    //   h1 : B*H floats (33.5 MB) -- front 4 MB aliased as tw between vq_topk and vq_pick
    //   h2 : B*H floats (33.5 MB)
    //   z  : B*D floats (16.8 MB)
    //   tail: az2(B) e2(K) idxI(B) vqp(512) recp(768)
    float* h1 = (float*)d_ws;
    float* h2 = h1 + (long)B_N * H_N;
    float* z  = h2 + (long)B_N * H_N;
    float* az2 = z + (long)B_N * D_N;
    float* e2  = az2 + B_N;
    int*   idxI = (int*)(e2 + K_N);
    float* vqp  = (float*)(idxI + B_N);
    float* recp = vqp + 512;
    float2* tw  = (float2*)h1;   // B*16 float2 = 4 MB, live only topk->pick (h1 dead there)

    // encoder (fp32 ascending-k fma chains == OpenBLAS sgemm microkernel semantics)
    enc1_kernel<<<B_N / 8, 256, 0, stream>>>(action, We1, be1, h1);
    gemm_rt<1, 0><<<dim3(2, B_N / 128), 256, 0, stream>>>(h1, We2, be2, h2, H_N, H_N, nullptr);
    gemm_rt<0, 0><<<dim3(1, B_N / 128), 256, 0, stream>>>(h2, We3, be3, z, H_N, D_N, nullptr);

    // np-exact squared norms (numpy pairwise_sum 8-accumulator tree)
    rowsum_kernel<<<B_N / 256, 256, 0, stream>>>(z, az2);
    embsum_kernel<<<K_N / 256, 256, 0, stream>>>(emb, e2);

    // vector quantizer: np-exact fp32 d2 + first-min argmin
    vq_topk<<<dim3(K_N / 128, B_N / 128), 256, 0, stream>>>(z, emb, e2, az2, tw);
    vq_pick<<<B_N / 256, 256, 0, stream>>>(tw, idxI, out + 3);
    vqloss_kernel<<<B_N / 64, 256, 0, stream>>>(z, emb, idxI, vqp);

    // decoder (dec1 gathers q = emb[idx]; h1/tw dead by now)
    gemm_rt<1, 1><<<dim3(2, B_N / 128), 256, 0, stream>>>(emb, Wd1, bd1, h1, D_N, H_N, idxI);
    gemm_rt<1, 0><<<dim3(2, B_N / 128), 256, 0, stream>>>(h1, Wd2, bd2, h2, H_N, H_N, nullptr);

    // head + losses
    head_kernel<<<(B_N * A_N) / 256, 256, 0, stream>>>(h2, Wh, bh, action, out + 3 + B_N, recp);
    final_kernel<<<1, 64, 0, stream>>>(vqp, recp, out);
}